// Round 12
// baseline (2677.622 us; speedup 1.0000x reference)
//
#include <hip/hip_runtime.h>
#include <hip/hip_bf16.h>

typedef __hip_bfloat16 bf16;
typedef __bf16 bf16x8 __attribute__((ext_vector_type(8)));
typedef float f32x4 __attribute__((ext_vector_type(4)));
typedef unsigned short u16;
typedef unsigned int u32;
typedef __attribute__((address_space(1))) const void* gptr_t;
typedef __attribute__((address_space(3))) void* lptr_t;

static constexpr int TOKS = 2048, DM = 2048, RL = 512, DF = 1024, SQ = 1024, NV = 32000;
static constexpr int CAP = 1536;                  // per-expert token capacity (22 sigma)
static constexpr long PL_X  = (long)TOKS * DM;    // 4M elems: [T][DM] plane
static constexpr long PL_C  = (long)TOKS * RL;    // 1M
static constexpr long PL_VT = 2l * 16 * 128 * 1024; // 4M: [b][h][d][s]
static constexpr long M4 = 4l * 1024 * 1024;
static constexpr long M2 = 2l * 1024 * 1024;

__device__ __forceinline__ float b2f(bf16 x){ return __bfloat162float(x); }
__device__ __forceinline__ bf16  f2b(float x){ return __float2bfloat16(x); }
__device__ __forceinline__ void split1(float x, u16& h, u16& l){
  bf16 hb = f2b(x);
  float r = x - b2f(hb);
  bf16 lb = f2b(r);
  h = *(u16*)&hb; l = *(u16*)&lb;
}

__device__ __forceinline__ float block_red(float v, int op){
  __shared__ float red[4];
  const int lane = threadIdx.x & 63, wv = threadIdx.x >> 6;
  #pragma unroll
  for (int off = 32; off > 0; off >>= 1){
    float o = __shfl_down(v, off, 64);
    v = op ? fmaxf(v, o) : v + o;
  }
  __syncthreads();
  if (lane == 0) red[wv] = v;
  __syncthreads();
  float r = red[0];
  #pragma unroll
  for (int i = 1; i < 4; ++i) r = op ? fmaxf(r, red[i]) : r + red[i];
  return r;
}

// ---- embedding gather + rmsnorm -> f32 residual ----
__global__ __launch_bounds__(256)
void embed_norm_k(const int* __restrict__ toks, const float* __restrict__ emb,
                  const float* __restrict__ w, float* __restrict__ h){
  const int t = blockIdx.x;
  const long tok = toks[t];
  const int base = threadIdx.x * 8;
  const float* ep = emb + tok * (long)DM + base;
  float4 va = *(const float4*)ep, vb = *(const float4*)(ep + 4);
  float v[8] = {va.x, va.y, va.z, va.w, vb.x, vb.y, vb.z, vb.w};
  float ss = 0.f;
  #pragma unroll
  for (int i = 0; i < 8; ++i) ss += v[i]*v[i];
  ss = block_red(ss, 0);
  const float inv = rsqrtf(ss / DM + 1e-6f);
  float4 wa = *(const float4*)(w + base), wb4 = *(const float4*)(w + base + 4);
  float wv[8] = {wa.x, wa.y, wa.z, wa.w, wb4.x, wb4.y, wb4.z, wb4.w};
  float* hp = h + (long)t * DM + base;
  #pragma unroll
  for (int i = 0; i < 8; ++i) hp[i] = v[i] * inv * wv[i];
}

// ---- rmsnorm f32 residual -> bf16 hi/lo planes ----
__global__ __launch_bounds__(256)
void rmsnorm_planes_k(const float* __restrict__ h, const float* __restrict__ w,
                      u16* __restrict__ hi, u16* __restrict__ lo){
  const int t = blockIdx.x;
  const int base = threadIdx.x * 8;
  const float* hp = h + (long)t * DM + base;
  float4 va = *(const float4*)hp, vb = *(const float4*)(hp + 4);
  float v[8] = {va.x, va.y, va.z, va.w, vb.x, vb.y, vb.z, vb.w};
  float ss = 0.f;
  #pragma unroll
  for (int i = 0; i < 8; ++i) ss += v[i]*v[i];
  ss = block_red(ss, 0);
  const float inv = rsqrtf(ss / DM + 1e-6f);
  float4 wa = *(const float4*)(w + base), wb4 = *(const float4*)(w + base + 4);
  float wv[8] = {wa.x, wa.y, wa.z, wa.w, wb4.x, wb4.y, wb4.z, wb4.w};
  u16 hvv[8], lvv[8];
  #pragma unroll
  for (int i = 0; i < 8; ++i) split1(v[i] * inv * wv[i], hvv[i], lvv[i]);
  *(int4*)(hi + (long)t * DM + base) = *(const int4*)hvv;
  *(int4*)(lo + (long)t * DM + base) = *(const int4*)lvv;
}

// ---- MoE gate in full f32 (rmsnorm fused) ----
__global__ __launch_bounds__(256)
void gate_k(const float* __restrict__ h, const float* __restrict__ nw,
            const float* __restrict__ Wg, float* __restrict__ gw){
  const int t = blockIdx.x;
  const int base = threadIdx.x * 8;
  const float* hp = h + (long)t * DM + base;
  float4 va = *(const float4*)hp, vb = *(const float4*)(hp + 4);
  float v[8] = {va.x, va.y, va.z, va.w, vb.x, vb.y, vb.z, vb.w};
  float ss = 0.f;
  #pragma unroll
  for (int i = 0; i < 8; ++i) ss += v[i]*v[i];
  ss = block_red(ss, 0);
  const float inv = rsqrtf(ss / DM + 1e-6f);
  float a[4] = {0.f, 0.f, 0.f, 0.f};
  #pragma unroll
  for (int i = 0; i < 8; ++i){
    const float xv = v[i] * inv * nw[base + i];
    #pragma unroll
    for (int e = 0; e < 4; ++e) a[e] += xv * Wg[(base + i)*4 + e];
  }
  #pragma unroll
  for (int e = 0; e < 4; ++e) a[e] = block_red(a[e], 0);
  if (threadIdx.x == 0){
    int i1 = 0;
    for (int e = 1; e < 4; ++e) if (a[e] > a[i1]) i1 = e;
    int i2 = -1;
    for (int e = 0; e < 4; ++e){ if (e == i1) continue; if (i2 < 0 || a[e] > a[i2]) i2 = e; }
    float g[4];
    const float m = fmaxf(fmaxf(a[0], a[1]), fmaxf(a[2], a[3]));
    float s = 0.f;
    for (int e = 0; e < 4; ++e){ g[e] = __expf(a[e] - m); s += g[e]; }
    for (int e = 0; e < 4; ++e) g[e] /= s;
    const float ns = g[i1] + g[i2];
    float* op = gw + (long)t * 4;
    op[0] = 0.f; op[1] = 0.f; op[2] = 0.f; op[3] = 0.f;
    op[i1] = g[i1] / ns; op[i2] = g[i2] / ns;
  }
}

// ---- per-expert token lists (deterministic order): 4 waves, one per expert ----
__global__ __launch_bounds__(256)
void build_lists_k(const float* __restrict__ gw, int* __restrict__ idx, int* __restrict__ cnt){
  const int e = threadIdx.x >> 6, lane = threadIdx.x & 63;
  int base = 0;
  for (int t0 = 0; t0 < TOKS; t0 += 64){
    const int t = t0 + lane;
    const bool sel = gw[(long)t * 4 + e] > 0.f;
    const unsigned long long m = __ballot(sel);
    const int pos = __popcll(m & ((1ull << lane) - 1ull));
    if (sel && base + pos < CAP) idx[e * CAP + base + pos] = t;
    base += (int)__popcll(m);
  }
  if (lane == 0) cnt[e] = base < CAP ? base : CAP;
}

// ---- gather selected rows (hi+lo planes) for an expert pair ----
__global__ __launch_bounds__(256)
void gather2_k(const u16* __restrict__ xph, const int* __restrict__ idx,
               const int* __restrict__ cnt, int ebase, u16* __restrict__ xg){
  const int e = blockIdx.x / CAP, r = blockIdx.x % CAP;
  if (r >= cnt[ebase + e]) return;
  const long t = idx[(long)(ebase + e) * CAP + r];
  const int c = threadIdx.x * 8;
  const long dst = ((long)e * 2 * CAP + r) * DM + c;
  *(int4*)(xg + dst) = *(const int4*)(xph + t * DM + c);
  *(int4*)(xg + dst + (long)CAP * DM) = *(const int4*)(xph + PL_X + t * DM + c);
}

// ---- gather selected rows (bf16 = hi plane) for all 4 experts ----
__global__ __launch_bounds__(256)
void gatherb_k(const u16* __restrict__ xph, const int* __restrict__ idx,
               const int* __restrict__ cnt, u16* __restrict__ xgb){
  const int e = blockIdx.x / CAP, r = blockIdx.x % CAP;
  if (r >= cnt[e]) return;
  const long t = idx[(long)e * CAP + r];
  const int c = threadIdx.x * 8;
  *(int4*)(xgb + ((long)e * CAP + r) * DM + c) = *(const int4*)(xph + t * DM + c);
}

// ---- row softmax over 1024 f32, packed hi/lo u16 IN PLACE ----
__global__ __launch_bounds__(256)
void softmax_pack_k(float* __restrict__ pf){
  const long row = blockIdx.x;
  const float* pr = pf + row * SQ;
  const int base = threadIdx.x * 4;
  float4 v4 = *(const float4*)(pr + base);
  float v[4] = {v4.x, v4.y, v4.z, v4.w};
  float m = fmaxf(fmaxf(v[0], v[1]), fmaxf(v[2], v[3]));
  m = block_red(m, 1);
  float s = 0.f;
  #pragma unroll
  for (int i = 0; i < 4; ++i){ v[i] = __expf(v[i] - m); s += v[i]; }
  s = block_red(s, 0);
  const float inv = 1.f / s;
  u16 hv[4], lv[4];
  #pragma unroll
  for (int i = 0; i < 4; ++i) split1(v[i] * inv, hv[i], lv[i]);
  u16* out = (u16*)pf + row * 2048;
  *(int2*)(out + base) = *(const int2*)hv;
  *(int2*)(out + 1024 + base) = *(const int2*)lv;
}

// ---- swiglu on f32 pair, packed hi/lo u16 IN PLACE over h1 ----
__global__ __launch_bounds__(256)
void swiglu_pack_k(float* __restrict__ h1, const float* __restrict__ h3){
  const int t = threadIdx.x;
  const long r = (long)blockIdx.x * 2 + (t >> 7);
  const int col = (t & 127) * 8;
  const float* p1 = h1 + r * 1024 + col;
  const float* p3 = h3 + r * 1024 + col;
  float4 a0 = *(const float4*)p1, a1 = *(const float4*)(p1 + 4);
  float4 b0 = *(const float4*)p3, b1 = *(const float4*)(p3 + 4);
  float a[8] = {a0.x, a0.y, a0.z, a0.w, a1.x, a1.y, a1.z, a1.w};
  float b[8] = {b0.x, b0.y, b0.z, b0.w, b1.x, b1.y, b1.z, b1.w};
  u16 hv[8], lv[8];
  #pragma unroll
  for (int j = 0; j < 8; ++j){
    const float y = (a[j] / (1.f + __expf(-a[j]))) * b[j];
    split1(y, hv[j], lv[j]);
  }
  __syncthreads();
  u16* out = (u16*)h1 + r * 2048;
  *(int4*)(out + col) = *(const int4*)hv;
  *(int4*)(out + 1024 + col) = *(const int4*)lv;
}

// ---- swiglu bf16 in place ----
__global__ __launch_bounds__(256)
void swiglu_bk(bf16* __restrict__ h1, const bf16* __restrict__ h3){
  const long i = ((long)blockIdx.x * 256 + threadIdx.x) * 8;
  union { int4 i4; bf16 b[8]; } x, y;
  x.i4 = *(const int4*)(h1 + i);
  y.i4 = *(const int4*)(h3 + i);
  #pragma unroll
  for (int j = 0; j < 8; ++j){
    const float a = b2f(x.b[j]);
    const float b = b2f(y.b[j]);
    x.b[j] = f2b((a / (1.f + __expf(-a))) * b);
  }
  *(int4*)(h1 + i) = x.i4;
}

// ---- transpose+split: f32 [K,N](ldin) -> hi/lo u16 [N,K](ldout), 64x64 tiles ----
__global__ __launch_bounds__(256)
void tsplit_k(const float* __restrict__ in, long inz, int ldin,
              u16* __restrict__ oh, u16* __restrict__ ol, long outz, int ldout, int ntx){
  __shared__ u16 lh[64][72], ll[64][72];
  const int z = blockIdx.z;
  in += (long)z * inz; oh += (long)z * outz; ol += (long)z * outz;
  const int bx = blockIdx.x % ntx, by = blockIdx.x / ntx;
  const int k0 = by * 64, n0 = bx * 64;
  const int t = threadIdx.x;
  {
    const int r = t >> 2, cb = (t & 3) * 16;
    const float* ip = in + (long)(k0 + r) * ldin + n0 + cb;
    #pragma unroll
    for (int i = 0; i < 16; i += 4){
      float4 v = *(const float4*)(ip + i);
      float a[4] = {v.x, v.y, v.z, v.w};
      #pragma unroll
      for (int j = 0; j < 4; ++j){
        u16 hv, lv; split1(a[j], hv, lv);
        lh[r][cb + i + j] = hv; ll[r][cb + i + j] = lv;
      }
    }
  }
  __syncthreads();
  {
    const int n = t >> 2, kb = (t & 3) * 16;
    u16 hv[16], lv[16];
    #pragma unroll
    for (int i = 0; i < 16; ++i){ hv[i] = lh[kb + i][n]; lv[i] = ll[kb + i][n]; }
    u16* po = oh + (long)(n0 + n) * ldout + k0 + kb;
    u16* pl = ol + (long)(n0 + n) * ldout + k0 + kb;
    *(int4*)po = *(const int4*)hv; *(int4*)(po + 8) = *(const int4*)(hv + 8);
    *(int4*)pl = *(const int4*)lv; *(int4*)(pl + 8) = *(const int4*)(lv + 8);
  }
}

// ---- transpose+convert: f32 [K,N](ldin) -> bf16 [N,K](ldout) ----
__global__ __launch_bounds__(256)
void tconv_k(const float* __restrict__ in, long inz, int ldin,
             bf16* __restrict__ out, long outz, int ldout, int ntx){
  __shared__ u16 lh[64][72];
  const int z = blockIdx.z;
  in += (long)z * inz; out += (long)z * outz;
  const int bx = blockIdx.x % ntx, by = blockIdx.x / ntx;
  const int k0 = by * 64, n0 = bx * 64;
  const int t = threadIdx.x;
  {
    const int r = t >> 2, cb = (t & 3) * 16;
    const float* ip = in + (long)(k0 + r) * ldin + n0 + cb;
    #pragma unroll
    for (int i = 0; i < 16; i += 4){
      float4 v = *(const float4*)(ip + i);
      float a[4] = {v.x, v.y, v.z, v.w};
      #pragma unroll
      for (int j = 0; j < 4; ++j){ bf16 hb = f2b(a[j]); lh[r][cb + i + j] = *(u16*)&hb; }
    }
  }
  __syncthreads();
  {
    const int n = t >> 2, kb = (t & 3) * 16;
    u16 hv[16];
    #pragma unroll
    for (int i = 0; i < 16; ++i) hv[i] = lh[kb + i][n];
    u16* po = (u16*)out + (long)(n0 + n) * ldout + k0 + kb;
    *(int4*)po = *(const int4*)hv; *(int4*)(po + 8) = *(const int4*)(hv + 8);
  }
}

// BK=64 swizzle (split kernel): chunk rotated by row&7 within 128B row.
__device__ __forceinline__ int swz64(int r, int c){
  return ((((c >> 3) + r) & 7) << 3) | (c & 7);
}
// BK=32 swizzle (wave kernel): chunk rotated by row>>1 within 64B row.
__device__ __forceinline__ int swz2(int r, int c){
  return ((((c >> 3) + (r >> 1)) & 3) << 3) | (c & 7);
}
// XCD-chunked bijective swizzle; M-tile fastest (ny = #M-tiles).
__device__ __forceinline__ int2 tile_xy(int ny){
  const int nwg = gridDim.x;
  const int wid = blockIdx.x;
  const int q = nwg >> 3, r = nwg & 7;
  const int xcd = wid & 7, pos = wid >> 3;
  const int lid = (xcd < r) ? (xcd*(q+1) + pos) : (r*(q+1) + (xcd - r)*q + pos);
  return make_int2(lid / ny, lid % ny);
}

// BK=64 DMA issue: 8 rows x 128B; source chunk inverse-rotated to match swz64 reads.
__device__ __forceinline__ void stage64(const u16* src, int ld, int rbase, int k0,
                                        u16* lp, int sub, int lane){
  const int r = sub * 8 + (lane >> 3);
  const int cs = ((lane & 7) - r) & 7;
  const u16* g = src + (long)(rbase + r) * ld + k0 + cs * 8;
  __builtin_amdgcn_global_load_lds((gptr_t)g, (lptr_t)(lp + sub * 512), 16, 0, 0);
}
// BK=32 DMA issue: 16 rows x 64B; source chunk inverse-rotated to match swz2 reads.
__device__ __forceinline__ void stage32(const u16* src, int ld, int rbase, int k0,
                                        u16* lp, int sub, int lane){
  const int r = sub * 16 + (lane >> 2);
  const int cs = ((lane & 3) - (r >> 1)) & 3;
  const u16* g = src + (long)(rbase + r) * ld + k0 + cs * 8;
  __builtin_amdgcn_global_load_lds((gptr_t)g, (lptr_t)(lp + sub * 512), 16, 0, 0);
}

// counted vmcnt wait + scheduling fence (rule 18)
template<int N> __device__ __forceinline__ void wait_vmcnt(){
  if constexpr (N == 0) asm volatile("s_waitcnt vmcnt(0)" ::: "memory");
  else if constexpr (N == 6) asm volatile("s_waitcnt vmcnt(6)" ::: "memory");
  __builtin_amdgcn_sched_barrier(0);
}
// raw workgroup barrier (no implicit vmcnt(0) drain)
__device__ __forceinline__ void barrier_raw(){
  __builtin_amdgcn_sched_barrier(0);
  asm volatile("" ::: "memory");
  __builtin_amdgcn_s_barrier();
  asm volatile("" ::: "memory");
  __builtin_amdgcn_sched_barrier(0);
}

// ==== SPLIT GEMM (round-10 proven): all-NT, BK=64, single-buffer, 3 MFMA ====
// OM: 0 f32 store*scale | 1 f32 += | 3 f32 += gate[row*gst]*v (non-atomic)
//     4 plane store | 5 vT plane store | 6 scatter += gate via rowmap
template<int MT, int OM>
__global__ __launch_bounds__(256)
void gemms_nt(const u16* __restrict__ Ah, const u16* __restrict__ Al, long ab, int lda,
              const u16* __restrict__ Bh, const u16* __restrict__ Bl, long bb, int ldb,
              void* __restrict__ Cv, long cb, int ldc, long cpl,
              int K, float scale, const float* __restrict__ aux, int gst, int ny,
              const int* __restrict__ rowmap, const int* __restrict__ cntp)
{
  __shared__ __align__(16) u16 ash[MT*32][64], asl[MT*32][64];
  __shared__ __align__(16) u16 bsh[128][64], bsl[128][64];
  const int z = blockIdx.z;
  Ah += (long)z * ab; Al += (long)z * ab;
  Bh += (long)z * bb; Bl += (long)z * bb;
  const int2 tt = tile_xy(ny);
  const int m0 = tt.y * (MT*32), n0 = tt.x * 128;
  int cntv = 1 << 30;
  if (cntp){ cntv = cntp[z]; if (m0 >= cntv) return; }
  const int tid = threadIdx.x, lane = tid & 63, wv = tid >> 6;
  const int wr = (wv >> 1) * (MT*16), wc = (wv & 1) * 64;
  const int fr = lane & 15, fk = (lane >> 4) * 8;

  f32x4 acc[MT][4] = {};
  constexpr int AI4 = MT * 4;

  for (int k0 = 0; k0 < K; k0 += 64){
    __syncthreads();
    #pragma unroll
    for (int ii = 0; ii < 2*AI4 + 32; ++ii){
      if ((ii & 3) != wv) continue;
      if (ii < AI4)             stage64(Ah, lda, m0, k0, &ash[0][0], ii, lane);
      else if (ii < 2*AI4)      stage64(Al, lda, m0, k0, &asl[0][0], ii - AI4, lane);
      else if (ii < 2*AI4 + 16) stage64(Bh, ldb, n0, k0, &bsh[0][0], ii - 2*AI4, lane);
      else                      stage64(Bl, ldb, n0, k0, &bsl[0][0], ii - 2*AI4 - 16, lane);
    }
    __syncthreads();
    bf16x8 ahf[MT][2], alf[MT][2], bhf[4][2], blf[4][2];
    #pragma unroll
    for (int mi = 0; mi < MT; ++mi){
      const int rr = wr + mi * 16 + fr;
      #pragma unroll
      for (int ks = 0; ks < 2; ++ks){
        const int sc = swz64(rr, ks * 32 + fk);
        ahf[mi][ks] = *(const bf16x8*)&ash[rr][sc];
        alf[mi][ks] = *(const bf16x8*)&asl[rr][sc];
      }
    }
    #pragma unroll
    for (int ni = 0; ni < 4; ++ni){
      const int rr = wc + ni * 16 + fr;
      #pragma unroll
      for (int ks = 0; ks < 2; ++ks){
        const int sc = swz64(rr, ks * 32 + fk);
        bhf[ni][ks] = *(const bf16x8*)&bsh[rr][sc];
        blf[ni][ks] = *(const bf16x8*)&bsl[rr][sc];
      }
    }
    #pragma unroll
    for (int mi = 0; mi < MT; ++mi)
      #pragma unroll
      for (int ni = 0; ni < 4; ++ni)
        #pragma unroll
        for (int ks = 0; ks < 2; ++ks){
          acc[mi][ni] = __builtin_amdgcn_mfma_f32_16x16x32_bf16(ahf[mi][ks], bhf[ni][ks], acc[mi][ni], 0, 0, 0);
          acc[mi][ni] = __builtin_amdgcn_mfma_f32_16x16x32_bf16(ahf[mi][ks], blf[ni][ks], acc[mi][ni], 0, 0, 0);
          acc[mi][ni] = __builtin_amdgcn_mfma_f32_16x16x32_bf16(alf[mi][ks], bhf[ni][ks], acc[mi][ni], 0, 0, 0);
        }
  }

  const int crow = (lane >> 4) * 4, ccol = lane & 15;
  #pragma unroll
  for (int mi = 0; mi < MT; ++mi){
    #pragma unroll
    for (int ni = 0; ni < 4; ++ni){
      const int gm0 = m0 + wr + mi * 16 + crow;
      const int gn = n0 + wc + ni * 16 + ccol;
      if (OM == 5){
        u16 hv[4], lv[4];
        #pragma unroll
        for (int j = 0; j < 4; ++j) split1(acc[mi][ni][j], hv[j], lv[j]);
        const long off = (((long)(gm0 >> 10) * 16 + (gn >> 7)) * 128 + (gn & 127)) * 1024 + (gm0 & 1023);
        u16* vt = (u16*)Cv;
        *(int2*)(vt + off) = *(const int2*)hv;
        *(int2*)(vt + cpl + off) = *(const int2*)lv;
      } else if (OM == 6){
        #pragma unroll
        for (int j = 0; j < 4; ++j){
          const int row = gm0 + j;
          if (row < cntv){
            const long t = rowmap[(long)z * CAP + row];
            ((float*)Cv)[t * ldc + gn] += aux[t * gst] * acc[mi][ni][j];
          }
        }
      } else {
        #pragma unroll
        for (int j = 0; j < 4; ++j){
          const long off = (long)z * cb + (long)(gm0 + j) * ldc + gn;
          const float v = acc[mi][ni][j];
          if (OM == 0)      ((float*)Cv)[off] = v * scale;
          else if (OM == 1) ((float*)Cv)[off] += v;
          else if (OM == 3) ((float*)Cv)[off] += aux[(long)(gm0 + j) * gst] * v;
          else { u16 hv, lv; split1(v, hv, lv); ((u16*)Cv)[off] = hv; ((u16*)Cv)[off + cpl] = lv; }
        }
      }
    }
  }
}

// ==== WAVE-TILE BF16 GEMM: block 128M x 256N, 4 waves in N, wave = 128x64 ====
// BK=32, 2-buffer counted-vmcnt DMA pipeline. A bf16 [M,K], B bf16 [N,K].
// OM: 0 bf16 store | 2 f32 store + bias (gn<nlim guard) | 7 atomic scatter via rowmap
template<int OM>
__global__ __launch_bounds__(256)
void gemmw_nt(const bf16* __restrict__ A, long ab, int lda,
              const bf16* __restrict__ B, long bb, int ldb,
              void* __restrict__ Cv, long cb, int ldc,
              int K, const float* __restrict__ aux, int gst, int ny, int nlim,
              const int* __restrict__ rowmap, const int* __restrict__ cntp)
{
  __shared__ __align__(16) u16 a_lds[2][128][32];
  __shared__ __align__(16) u16 b_lds[2][256][32];
  const int z = blockIdx.z;
  A += (long)z * ab; B += (long)z * bb;
  const int2 tt = tile_xy(ny);
  const int m0 = tt.y * 128, n0 = tt.x * 256;
  int cntv = 1 << 30;
  if (cntp){ cntv = cntp[z]; if (m0 >= cntv) return; }
  const int tid = threadIdx.x, lane = tid & 63, wv = tid >> 6;
  const int wc = wv * 64;
  const int fr = lane & 15, fk = (lane >> 4) * 8;

  f32x4 acc[8][4] = {};

  auto STAGE = [&](int bf, int k0){
    #pragma unroll
    for (int ii = 0; ii < 24; ++ii){            // 8 A-subs + 16 B-subs, 6 per wave
      if ((ii & 3) != wv) continue;
      if (ii < 8) stage32((const u16*)A, lda, m0, k0, &a_lds[bf][0][0], ii, lane);
      else        stage32((const u16*)B, ldb, n0, k0, &b_lds[bf][0][0], ii - 8, lane);
    }
  };

  STAGE(0, 0);
  int cur = 0;
  for (int k0 = 0; k0 < K; k0 += 32){
    if (k0 + 32 < K){ STAGE(cur ^ 1, k0 + 32); wait_vmcnt<6>(); }
    else              wait_vmcnt<0>();
    barrier_raw();
    bf16x8 bfv[4];
    #pragma unroll
    for (int ni = 0; ni < 4; ++ni){
      const int rr = wc + ni * 16 + fr;
      bfv[ni] = *(const bf16x8*)&b_lds[cur][rr][swz2(rr, fk)];
    }
    #pragma unroll
    for (int mih = 0; mih < 2; ++mih){
      bf16x8 af[4];
      #pragma unroll
      for (int mj = 0; mj < 4; ++mj){
        const int rr = mih * 64 + mj * 16 + fr;
        af[mj] = *(const bf16x8*)&a_lds[cur][rr][swz2(rr, fk)];
      }
      #pragma unroll
      for (int mj = 0; mj < 4; ++mj)
        #pragma unroll
        for (int ni = 0; ni < 4; ++ni)
          acc[mih*4 + mj][ni] = __builtin_amdgcn_mfma_f32_16x16x32_bf16(af[mj], bfv[ni], acc[mih*4 + mj][ni], 0, 0, 0);
    }
    barrier_raw();
    cur ^= 1;
  }

  const int crow = (lane >> 4) * 4, ccol = lane & 15;
  #pragma unroll
  for (int mi = 0; mi < 8; ++mi){
    #pragma unroll
    for (int ni = 0; ni < 4; ++ni){
      const int gm0 = m0 + mi * 16 + crow;
      const int gn = n0 + wc + ni * 16 + ccol;
      #pragma unroll
      for (int j = 0; j < 4; ++j){
        const float v = acc[mi][ni][j];
        if (OM == 7){
          const int row = gm0 + j;
          if (row < cntv){
            const long t = rowmap[(long)z * CAP + row];
            atomicAdd(&((float*)Cv)[t * ldc + gn], aux[t * gst + z] * v);
          }
        } else if (OM == 2){
          if (gn < nlim){
            const long off = (long)z * cb + (long)(gm0 + j) * ldc + gn;
            ((float*)Cv)[off] = v + aux[gn];
          }
        } else {
          const long off = (long)z * cb + (long)(gm0 + j) * ldc + gn;
          ((bf16*)Cv)[off] = f2b(v);
        }
      }
    }
  }
}

extern "C" void kernel_launch(void* const* d_in, const int* in_sizes, int n_in,
                              void* d_out, int out_size, void* d_ws, size_t ws_size,
                              hipStream_t stream)
{
  (void)in_sizes; (void)n_in; (void)out_size; (void)ws_size;
  const int*   toks = (const int*)d_in[0];
  const float* emb  = (const float*)d_in[1];
  const float* enw  = (const float*)d_in[2];
  const float* nw   = (const float*)d_in[3];
  const float* Wq   = (const float*)d_in[4];
  const float* Wdkv = (const float*)d_in[5];
  const float* Wuk  = (const float*)d_in[6];
  const float* Wuv  = (const float*)d_in[7];
  const float* Wo   = (const float*)d_in[8];
  const float* Wg   = (const float*)d_in[9];
  const float* W1   = (const float*)d_in[10];
  const float* W3   = (const float*)d_in[11];
  const float* W2   = (const float*)d_in[12];
  const float* hnw  = (const float*)d_in[13];
  const float* hW   = (const float*)d_in[14];
  const float* hb   = (const float*)d_in[15];

  const size_t MB = 1ull << 20;
  char* ws = (char*)d_ws;
  float* h    = (float*)(ws);               // [0,16)
  float* gw   = (float*)(ws + 16*MB);       // gates [T][4] (32 KB)
  int*   idx  = (int*)(ws + 16*MB + 128*1024); // [4][CAP]
  int*   cnt  = (int*)(ws + 16*MB + 256*1024); // [4]
  u16*   xph  = (u16*)(ws + 17*MB);         // [17,33)  x planes (lo = +PL_X)
  u16*   wpl  = (u16*)(ws + 33*MB);         // [33,49)  weight planes scratch
  u16*   qph  = (u16*)(ws + 49*MB);         // [49,65)
  u16*   cph  = (u16*)(ws + 65*MB);         // [65,69)
  u16*   kph  = (u16*)(ws + 69*MB);         // [69,85)
  u16*   vtp  = (u16*)(ws + 85*MB);         // [85,101) v transposed planes
  u16*   oph  = (u16*)(ws + 101*MB);        // [101,117)
  float* pf   = (float*)(ws + 17*MB);       // [17,49)  scores (attn core)
  u16*   xg   = (u16*)(ws + 49*MB);         // l0 MoE: gathered pair planes = 24MB
  float* h1f  = (float*)(ws + 73*MB);       // [73,85)
  float* h3f  = (float*)(ws + 85*MB);       // [85,97)
  bf16*  wT   = (bf16*)(ws + 33*MB);        // l1 bf16 weights [33,49)
  u16*   xgb  = (u16*)(ws + 49*MB);         // l1: gathered bf16 = 24MB
  bf16*  h1b  = (bf16*)(ws + 73*MB);        // [73,85)
  bf16*  h3b  = (bf16*)(ws + 85*MB);        // [85,97)
  bf16*  whT  = (bf16*)(ws + 33*MB);        // head wT half: 16128 rows x 2048 = 66MB [33,99.1)

  const float qscale = 0.08838834764831845f;

  embed_norm_k<<<TOKS, 256, 0, stream>>>(toks, emb, enw, h);

  for (int l = 0; l < 2; ++l){
    const float* nwl = nw + (long)l * DM;
    rmsnorm_planes_k<<<TOKS, 256, 0, stream>>>(h, nwl, xph, xph + PL_X);

    // q = x @ Wq
    tsplit_k<<<1024, 256, 0, stream>>>(Wq + (long)l*DM*DM, 0, DM, wpl, wpl + M4, 0, DM, 32);
    gemms_nt<2,4><<<dim3(512,1,1), 256, 0, stream>>>(xph, xph + PL_X, 0, DM, wpl, wpl + M4, 0, DM,
        qph, 0, DM, PL_X, DM, 1.f, nullptr, 0, 32, nullptr, nullptr);
    // c = x @ Wdkv
    tsplit_k<<<256, 256, 0, stream>>>(Wdkv + (long)l*DM*RL, 0, RL, wpl, wpl + M2, 0, DM, 8);
    gemms_nt<2,4><<<dim3(128,1,1), 256, 0, stream>>>(xph, xph + PL_X, 0, DM, wpl, wpl + M2, 0, DM,
        cph, 0, RL, PL_C, DM, 1.f, nullptr, 0, 32, nullptr, nullptr);
    // k = c @ Wuk
    tsplit_k<<<256, 256, 0, stream>>>(Wuk + (long)l*RL*DM, 0, DM, wpl, wpl + M2, 0, RL, 32);
    gemms_nt<2,4><<<dim3(512,1,1), 256, 0, stream>>>(cph, cph + PL_C, 0, RL, wpl, wpl + M2, 0, RL,
        kph, 0, DM, PL_X, RL, 1.f, nullptr, 0, 32, nullptr, nullptr);
    // v = c @ Wuv -> vT planes
    tsplit_k<<<256, 256, 0, stream>>>(Wuv + (long)l*RL*DM, 0, DM, wpl, wpl + M2, 0, RL, 32);
    gemms_nt<2,5><<<dim3(512,1,1), 256, 0, stream>>>(cph, cph + PL_C, 0, RL, wpl, wpl + M2, 0, RL,
        vtp, 0, 0, PL_VT, RL, 1.f, nullptr, 0, 32, nullptr, nullptr);

    // attention core: per batch x 8-head group
    for (int b = 0; b < 2; ++b){
      for (int hg = 0; hg < 2; ++hg){
        const long qo = (long)b*SQ*DM + hg*1024;
        gemms_nt<4,0><<<dim3(64,1,8), 256, 0, stream>>>(qph + qo, qph + PL_X + qo, 128, DM,
            kph + qo, kph + PL_X + qo, 128, DM,
            pf, (long)SQ*SQ, SQ, 0, 128, qscale, nullptr, 0, 8, nullptr, nullptr);
        softmax_pack_k<<<8*SQ, 256, 0, stream>>>(pf);
        const long vo = ((long)b*16 + hg*8) * 128 * 1024;
        gemms_nt<1,4><<<dim3(32,1,8), 256, 0, stream>>>((const u16*)pf, (const u16*)pf + 1024,
            1024l*2048, 2048,
            vtp + vo, vtp + PL_VT + vo, 128l*1024, 1024,
            oph + (long)b*SQ*DM + hg*1024, 128, DM, PL_X, SQ, 1.f, nullptr, 0, 32, nullptr, nullptr);
      }
    }

    // h += o @ Wo
    tsplit_k<<<1024, 256, 0, stream>>>(Wo + (long)l*DM*DM, 0, DM, wpl, wpl + M4, 0, DM, 32);
    gemms_nt<2,1><<<dim3(512,1,1), 256, 0, stream>>>(oph, oph + PL_X, 0, DM, wpl, wpl + M4, 0, DM,
        h, 0, DM, 0, DM, 1.f, nullptr, 0, 32, nullptr, nullptr);

    gate_k<<<TOKS, 256, 0, stream>>>(h, nwl, Wg + (long)l*DM*4, gw);
    build_lists_k<<<1, 256, 0, stream>>>(gw, idx, cnt);
    rmsnorm_planes_k<<<TOKS, 256, 0, stream>>>(h, nwl, xph, xph + PL_X);

    if (l == 0){
      // precise sparse MoE, expert pairs; deterministic scatter-accumulate
      for (int p2 = 0; p2 < 2; ++p2){
        const int ebase = p2 * 2;
        const long wo13 = ((long)l*4 + ebase) * (long)DM * DF;
        gather2_k<<<2*CAP, 256, 0, stream>>>(xph, idx, cnt, ebase, xg);
        tsplit_k<<<dim3(512,1,2), 256, 0, stream>>>(W1 + wo13, (long)DM*DF, DF, wpl, wpl + M4, M2, DM, 16);
        gemms_nt<2,0><<<dim3(192,1,2), 256, 0, stream>>>(xg, xg + (long)CAP*DM, 2l*CAP*DM, DM,
            wpl, wpl + M4, M2, DM, h1f, (long)CAP*DF, DF, 0, DM, 1.f, nullptr, 0, 24,
            nullptr, cnt + ebase);
        tsplit_k<<<dim3(512,1,2), 256, 0, stream>>>(W3 + wo13, (long)DM*DF, DF, wpl, wpl + M4, M2, DM, 16);
        gemms_nt<2,0><<<dim3(192,1,2), 256, 0, stream>>>(xg, xg + (long)CAP*DM, 2l*CAP*DM, DM,
            wpl, wpl + M4, M2, DM, h3f, (long)CAP*DF, DF, 0, DM, 1.f, nullptr, 0, 24,
            nullptr, cnt + ebase);
        swiglu_pack_k<<<CAP, 256, 0, stream>>>(h1f, h3f);
        tsplit_k<<<dim3(512,1,2), 256, 0, stream>>>(W2 + ((long)l*4 + ebase)*(long)DF*DM, (long)DF*DM, DM,
            wpl, wpl + M4, M2, DF, 32);
        for (int ei = 0; ei < 2; ++ei){
          gemms_nt<2,6><<<dim3(384,1,1), 256, 0, stream>>>(
              (const u16*)h1f + (long)ei*CAP*2048, (const u16*)h1f + (long)ei*CAP*2048 + 1024,
              0, 2048, wpl + (long)ei*M2, wpl + M4 + (long)ei*M2, 0, DF,
              h, 0, DM, 0, DF, 1.f, gw + ebase + ei, 4, 24,
              idx + (ebase + ei)*CAP, cnt + ebase + ei);
        }
      }
    } else {
      // fast sparse bf16 MoE, all 4 experts (z=4); atomic scatter (head-only consumer)
      gatherb_k<<<4*CAP, 256, 0, stream>>>(xph, idx, cnt, xgb);
      tconv_k<<<dim3(512,1,4), 256, 0, stream>>>(W1 + (long)l*4*DM*DF, (long)DM*DF, DF, wT, M2, DM, 16);
      gemmw_nt<0><<<dim3(48,1,4), 256, 0, stream>>>((const bf16*)xgb, (long)CAP*DM, DM, wT, M2, DM,
          h1b, (long)CAP*DF, DF, DM, nullptr, 0, 12, 1<<30, nullptr, cnt);
      tconv_k<<<dim3(512,1,4), 256, 0, stream>>>(W3 + (long)l*4*DM*DF, (long)DM*DF, DF, wT, M2, DM, 16);
      gemmw_nt<0><<<dim3(48,1,4), 256, 0, stream>>>((const bf16*)xgb, (long)CAP*DM, DM, wT, M2, DM,
          h3b, (long)CAP*DF, DF, DM, nullptr, 0, 12, 1<<30, nullptr, cnt);
      swiglu_bk<<<(4*CAP*DF)/2048, 256, 0, stream>>>(h1b, h3b);
      tconv_k<<<dim3(512,1,4), 256, 0, stream>>>(W2 + (long)l*4*DF*DM, (long)DF*DM, DM, wT, M2, DF, 32);
      gemmw_nt<7><<<dim3(96,1,4), 256, 0, stream>>>(h1b, (long)CAP*DF, DF, wT, M2, DF,
          h, 0, DM, DF, gw, 4, 12, 1<<30, idx, cnt);
    }
  }

  // head: two N-halves; wave-tile GEMM, N padded to 63x256 tiles (stores guarded)
  rmsnorm_planes_k<<<TOKS, 256, 0, stream>>>(h, hnw, xph, xph + PL_X);
  for (int half = 0; half < 2; ++half){
    tconv_k<<<8000, 256, 0, stream>>>(hW + half*16000, 0, NV, whT, 0, DM, 250);
    gemmw_nt<2><<<dim3(1008,1,1), 256, 0, stream>>>((const bf16*)xph, 0, DM, whT, 0, DM,
        (float*)d_out + half*16000, 0, NV, DM, hb + half*16000, 0, 16, 16000, nullptr, nullptr);
  }
}

// Round 13
// 2174.532 us; speedup vs baseline: 1.2314x; 1.2314x over previous
//
#include <hip/hip_runtime.h>
#include <hip/hip_bf16.h>

typedef __hip_bfloat16 bf16;
typedef __bf16 bf16x8 __attribute__((ext_vector_type(8)));
typedef float f32x4 __attribute__((ext_vector_type(4)));
typedef unsigned short u16;
typedef unsigned int u32;
typedef __attribute__((address_space(1))) const void* gptr_t;
typedef __attribute__((address_space(3))) void* lptr_t;

static constexpr int TOKS = 2048, DM = 2048, RL = 512, DF = 1024, SQ = 1024, NV = 32000;
static constexpr int CAP = 1536;                  // per-expert token capacity (22 sigma)
static constexpr long PL_X  = (long)TOKS * DM;    // 4M elems: [T][DM] plane
static constexpr long PL_C  = (long)TOKS * RL;    // 1M
static constexpr long PL_VT = 2l * 16 * 128 * 1024; // 4M: [b][h][d][s]
static constexpr long M4 = 4l * 1024 * 1024;
static constexpr long M2 = 2l * 1024 * 1024;

__device__ __forceinline__ float b2f(bf16 x){ return __bfloat162float(x); }
__device__ __forceinline__ bf16  f2b(float x){ return __float2bfloat16(x); }
__device__ __forceinline__ void split1(float x, u16& h, u16& l){
  bf16 hb = f2b(x);
  float r = x - b2f(hb);
  bf16 lb = f2b(r);
  h = *(u16*)&hb; l = *(u16*)&lb;
}

__device__ __forceinline__ float block_red(float v, int op){
  __shared__ float red[4];
  const int lane = threadIdx.x & 63, wv = threadIdx.x >> 6;
  #pragma unroll
  for (int off = 32; off > 0; off >>= 1){
    float o = __shfl_down(v, off, 64);
    v = op ? fmaxf(v, o) : v + o;
  }
  __syncthreads();
  if (lane == 0) red[wv] = v;
  __syncthreads();
  float r = red[0];
  #pragma unroll
  for (int i = 1; i < 4; ++i) r = op ? fmaxf(r, red[i]) : r + red[i];
  return r;
}

// ---- embedding gather + rmsnorm -> f32 residual ----
__global__ __launch_bounds__(256)
void embed_norm_k(const int* __restrict__ toks, const float* __restrict__ emb,
                  const float* __restrict__ w, float* __restrict__ h){
  const int t = blockIdx.x;
  const long tok = toks[t];
  const int base = threadIdx.x * 8;
  const float* ep = emb + tok * (long)DM + base;
  float4 va = *(const float4*)ep, vb = *(const float4*)(ep + 4);
  float v[8] = {va.x, va.y, va.z, va.w, vb.x, vb.y, vb.z, vb.w};
  float ss = 0.f;
  #pragma unroll
  for (int i = 0; i < 8; ++i) ss += v[i]*v[i];
  ss = block_red(ss, 0);
  const float inv = rsqrtf(ss / DM + 1e-6f);
  float4 wa = *(const float4*)(w + base), wb4 = *(const float4*)(w + base + 4);
  float wv[8] = {wa.x, wa.y, wa.z, wa.w, wb4.x, wb4.y, wb4.z, wb4.w};
  float* hp = h + (long)t * DM + base;
  #pragma unroll
  for (int i = 0; i < 8; ++i) hp[i] = v[i] * inv * wv[i];
}

// ---- rmsnorm f32 residual -> bf16 hi/lo planes ----
__global__ __launch_bounds__(256)
void rmsnorm_planes_k(const float* __restrict__ h, const float* __restrict__ w,
                      u16* __restrict__ hi, u16* __restrict__ lo){
  const int t = blockIdx.x;
  const int base = threadIdx.x * 8;
  const float* hp = h + (long)t * DM + base;
  float4 va = *(const float4*)hp, vb = *(const float4*)(hp + 4);
  float v[8] = {va.x, va.y, va.z, va.w, vb.x, vb.y, vb.z, vb.w};
  float ss = 0.f;
  #pragma unroll
  for (int i = 0; i < 8; ++i) ss += v[i]*v[i];
  ss = block_red(ss, 0);
  const float inv = rsqrtf(ss / DM + 1e-6f);
  float4 wa = *(const float4*)(w + base), wb4 = *(const float4*)(w + base + 4);
  float wv[8] = {wa.x, wa.y, wa.z, wa.w, wb4.x, wb4.y, wb4.z, wb4.w};
  u16 hvv[8], lvv[8];
  #pragma unroll
  for (int i = 0; i < 8; ++i) split1(v[i] * inv * wv[i], hvv[i], lvv[i]);
  *(int4*)(hi + (long)t * DM + base) = *(const int4*)hvv;
  *(int4*)(lo + (long)t * DM + base) = *(const int4*)lvv;
}

// ---- MoE gate in full f32 (rmsnorm fused) ----
__global__ __launch_bounds__(256)
void gate_k(const float* __restrict__ h, const float* __restrict__ nw,
            const float* __restrict__ Wg, float* __restrict__ gw){
  const int t = blockIdx.x;
  const int base = threadIdx.x * 8;
  const float* hp = h + (long)t * DM + base;
  float4 va = *(const float4*)hp, vb = *(const float4*)(hp + 4);
  float v[8] = {va.x, va.y, va.z, va.w, vb.x, vb.y, vb.z, vb.w};
  float ss = 0.f;
  #pragma unroll
  for (int i = 0; i < 8; ++i) ss += v[i]*v[i];
  ss = block_red(ss, 0);
  const float inv = rsqrtf(ss / DM + 1e-6f);
  float a[4] = {0.f, 0.f, 0.f, 0.f};
  #pragma unroll
  for (int i = 0; i < 8; ++i){
    const float xv = v[i] * inv * nw[base + i];
    #pragma unroll
    for (int e = 0; e < 4; ++e) a[e] += xv * Wg[(base + i)*4 + e];
  }
  #pragma unroll
  for (int e = 0; e < 4; ++e) a[e] = block_red(a[e], 0);
  if (threadIdx.x == 0){
    int i1 = 0;
    for (int e = 1; e < 4; ++e) if (a[e] > a[i1]) i1 = e;
    int i2 = -1;
    for (int e = 0; e < 4; ++e){ if (e == i1) continue; if (i2 < 0 || a[e] > a[i2]) i2 = e; }
    float g[4];
    const float m = fmaxf(fmaxf(a[0], a[1]), fmaxf(a[2], a[3]));
    float s = 0.f;
    for (int e = 0; e < 4; ++e){ g[e] = __expf(a[e] - m); s += g[e]; }
    for (int e = 0; e < 4; ++e) g[e] /= s;
    const float ns = g[i1] + g[i2];
    float* op = gw + (long)t * 4;
    op[0] = 0.f; op[1] = 0.f; op[2] = 0.f; op[3] = 0.f;
    op[i1] = g[i1] / ns; op[i2] = g[i2] / ns;
  }
}

// ---- per-expert token lists (deterministic order): 4 waves, one per expert ----
__global__ __launch_bounds__(256)
void build_lists_k(const float* __restrict__ gw, int* __restrict__ idx, int* __restrict__ cnt){
  const int e = threadIdx.x >> 6, lane = threadIdx.x & 63;
  int base = 0;
  for (int t0 = 0; t0 < TOKS; t0 += 64){
    const int t = t0 + lane;
    const bool sel = gw[(long)t * 4 + e] > 0.f;
    const unsigned long long m = __ballot(sel);
    const int pos = __popcll(m & ((1ull << lane) - 1ull));
    if (sel && base + pos < CAP) idx[e * CAP + base + pos] = t;
    base += (int)__popcll(m);
  }
  if (lane == 0) cnt[e] = base < CAP ? base : CAP;
}

// ---- gather selected rows (hi+lo planes) for an expert pair ----
__global__ __launch_bounds__(256)
void gather2_k(const u16* __restrict__ xph, const int* __restrict__ idx,
               const int* __restrict__ cnt, int ebase, u16* __restrict__ xg){
  const int e = blockIdx.x / CAP, r = blockIdx.x % CAP;
  if (r >= cnt[ebase + e]) return;
  const long t = idx[(long)(ebase + e) * CAP + r];
  const int c = threadIdx.x * 8;
  const long dst = ((long)e * 2 * CAP + r) * DM + c;
  *(int4*)(xg + dst) = *(const int4*)(xph + t * DM + c);
  *(int4*)(xg + dst + (long)CAP * DM) = *(const int4*)(xph + PL_X + t * DM + c);
}

// ---- gather selected rows (bf16 = hi plane) for all 4 experts ----
__global__ __launch_bounds__(256)
void gatherb_k(const u16* __restrict__ xph, const int* __restrict__ idx,
               const int* __restrict__ cnt, u16* __restrict__ xgb){
  const int e = blockIdx.x / CAP, r = blockIdx.x % CAP;
  if (r >= cnt[e]) return;
  const long t = idx[(long)e * CAP + r];
  const int c = threadIdx.x * 8;
  *(int4*)(xgb + ((long)e * CAP + r) * DM + c) = *(const int4*)(xph + t * DM + c);
}

// ---- row softmax over 1024 f32, packed hi/lo u16 IN PLACE ----
__global__ __launch_bounds__(256)
void softmax_pack_k(float* __restrict__ pf){
  const long row = blockIdx.x;
  const float* pr = pf + row * SQ;
  const int base = threadIdx.x * 4;
  float4 v4 = *(const float4*)(pr + base);
  float v[4] = {v4.x, v4.y, v4.z, v4.w};
  float m = fmaxf(fmaxf(v[0], v[1]), fmaxf(v[2], v[3]));
  m = block_red(m, 1);
  float s = 0.f;
  #pragma unroll
  for (int i = 0; i < 4; ++i){ v[i] = __expf(v[i] - m); s += v[i]; }
  s = block_red(s, 0);
  const float inv = 1.f / s;
  u16 hv[4], lv[4];
  #pragma unroll
  for (int i = 0; i < 4; ++i) split1(v[i] * inv, hv[i], lv[i]);
  u16* out = (u16*)pf + row * 2048;
  *(int2*)(out + base) = *(const int2*)hv;
  *(int2*)(out + 1024 + base) = *(const int2*)lv;
}

// ---- swiglu on f32 pair, packed hi/lo u16 IN PLACE over h1 ----
__global__ __launch_bounds__(256)
void swiglu_pack_k(float* __restrict__ h1, const float* __restrict__ h3){
  const int t = threadIdx.x;
  const long r = (long)blockIdx.x * 2 + (t >> 7);
  const int col = (t & 127) * 8;
  const float* p1 = h1 + r * 1024 + col;
  const float* p3 = h3 + r * 1024 + col;
  float4 a0 = *(const float4*)p1, a1 = *(const float4*)(p1 + 4);
  float4 b0 = *(const float4*)p3, b1 = *(const float4*)(p3 + 4);
  float a[8] = {a0.x, a0.y, a0.z, a0.w, a1.x, a1.y, a1.z, a1.w};
  float b[8] = {b0.x, b0.y, b0.z, b0.w, b1.x, b1.y, b1.z, b1.w};
  u16 hv[8], lv[8];
  #pragma unroll
  for (int j = 0; j < 8; ++j){
    const float y = (a[j] / (1.f + __expf(-a[j]))) * b[j];
    split1(y, hv[j], lv[j]);
  }
  __syncthreads();
  u16* out = (u16*)h1 + r * 2048;
  *(int4*)(out + col) = *(const int4*)hv;
  *(int4*)(out + 1024 + col) = *(const int4*)lv;
}

// ---- swiglu bf16 in place ----
__global__ __launch_bounds__(256)
void swiglu_bk(bf16* __restrict__ h1, const bf16* __restrict__ h3){
  const long i = ((long)blockIdx.x * 256 + threadIdx.x) * 8;
  union { int4 i4; bf16 b[8]; } x, y;
  x.i4 = *(const int4*)(h1 + i);
  y.i4 = *(const int4*)(h3 + i);
  #pragma unroll
  for (int j = 0; j < 8; ++j){
    const float a = b2f(x.b[j]);
    const float b = b2f(y.b[j]);
    x.b[j] = f2b((a / (1.f + __expf(-a))) * b);
  }
  *(int4*)(h1 + i) = x.i4;
}

// ---- transpose+split: f32 [K,N](ldin) -> hi/lo u16 [N,K](ldout), 64x64 tiles ----
__global__ __launch_bounds__(256)
void tsplit_k(const float* __restrict__ in, long inz, int ldin,
              u16* __restrict__ oh, u16* __restrict__ ol, long outz, int ldout, int ntx){
  __shared__ u16 lh[64][72], ll[64][72];
  const int z = blockIdx.z;
  in += (long)z * inz; oh += (long)z * outz; ol += (long)z * outz;
  const int bx = blockIdx.x % ntx, by = blockIdx.x / ntx;
  const int k0 = by * 64, n0 = bx * 64;
  const int t = threadIdx.x;
  {
    const int r = t >> 2, cb = (t & 3) * 16;
    const float* ip = in + (long)(k0 + r) * ldin + n0 + cb;
    #pragma unroll
    for (int i = 0; i < 16; i += 4){
      float4 v = *(const float4*)(ip + i);
      float a[4] = {v.x, v.y, v.z, v.w};
      #pragma unroll
      for (int j = 0; j < 4; ++j){
        u16 hv, lv; split1(a[j], hv, lv);
        lh[r][cb + i + j] = hv; ll[r][cb + i + j] = lv;
      }
    }
  }
  __syncthreads();
  {
    const int n = t >> 2, kb = (t & 3) * 16;
    u16 hv[16], lv[16];
    #pragma unroll
    for (int i = 0; i < 16; ++i){ hv[i] = lh[kb + i][n]; lv[i] = ll[kb + i][n]; }
    u16* po = oh + (long)(n0 + n) * ldout + k0 + kb;
    u16* pl = ol + (long)(n0 + n) * ldout + k0 + kb;
    *(int4*)po = *(const int4*)hv; *(int4*)(po + 8) = *(const int4*)(hv + 8);
    *(int4*)pl = *(const int4*)lv; *(int4*)(pl + 8) = *(const int4*)(lv + 8);
  }
}

// ---- transpose+convert: f32 [K,N](ldin) -> bf16 [N,K](ldout) ----
__global__ __launch_bounds__(256)
void tconv_k(const float* __restrict__ in, long inz, int ldin,
             bf16* __restrict__ out, long outz, int ldout, int ntx){
  __shared__ u16 lh[64][72];
  const int z = blockIdx.z;
  in += (long)z * inz; out += (long)z * outz;
  const int bx = blockIdx.x % ntx, by = blockIdx.x / ntx;
  const int k0 = by * 64, n0 = bx * 64;
  const int t = threadIdx.x;
  {
    const int r = t >> 2, cb = (t & 3) * 16;
    const float* ip = in + (long)(k0 + r) * ldin + n0 + cb;
    #pragma unroll
    for (int i = 0; i < 16; i += 4){
      float4 v = *(const float4*)(ip + i);
      float a[4] = {v.x, v.y, v.z, v.w};
      #pragma unroll
      for (int j = 0; j < 4; ++j){ bf16 hb = f2b(a[j]); lh[r][cb + i + j] = *(u16*)&hb; }
    }
  }
  __syncthreads();
  {
    const int n = t >> 2, kb = (t & 3) * 16;
    u16 hv[16];
    #pragma unroll
    for (int i = 0; i < 16; ++i) hv[i] = lh[kb + i][n];
    u16* po = (u16*)out + (long)(n0 + n) * ldout + k0 + kb;
    *(int4*)po = *(const int4*)hv; *(int4*)(po + 8) = *(const int4*)(hv + 8);
  }
}

// BK=64 swizzle (split kernel): chunk rotated by row&7 within 128B row.
__device__ __forceinline__ int swz64(int r, int c){
  return ((((c >> 3) + r) & 7) << 3) | (c & 7);
}
// BK=32 swizzle (plain kernel): chunk rotated by row>>1 within 64B row.
__device__ __forceinline__ int swz2(int r, int c){
  return ((((c >> 3) + (r >> 1)) & 3) << 3) | (c & 7);
}
// XCD-chunked bijective swizzle; M-tile fastest (ny = #M-tiles).
__device__ __forceinline__ int2 tile_xy(int ny){
  const int nwg = gridDim.x;
  const int wid = blockIdx.x;
  const int q = nwg >> 3, r = nwg & 7;
  const int xcd = wid & 7, pos = wid >> 3;
  const int lid = (xcd < r) ? (xcd*(q+1) + pos) : (r*(q+1) + (xcd - r)*q + pos);
  return make_int2(lid / ny, lid % ny);
}

// BK=64 DMA issue: 8 rows x 128B; source chunk inverse-rotated to match swz64 reads.
__device__ __forceinline__ void stage64(const u16* src, int ld, int rbase, int k0,
                                        u16* lp, int sub, int lane){
  const int r = sub * 8 + (lane >> 3);
  const int cs = ((lane & 7) - r) & 7;
  const u16* g = src + (long)(rbase + r) * ld + k0 + cs * 8;
  __builtin_amdgcn_global_load_lds((gptr_t)g, (lptr_t)(lp + sub * 512), 16, 0, 0);
}
// BK=32 DMA issue: 16 rows x 64B; source chunk inverse-rotated to match swz2 reads.
__device__ __forceinline__ void stage32(const u16* src, int ld, int rbase, int k0,
                                        u16* lp, int sub, int lane){
  const int r = sub * 16 + (lane >> 2);
  const int cs = ((lane & 3) - (r >> 1)) & 3;
  const u16* g = src + (long)(rbase + r) * ld + k0 + cs * 8;
  __builtin_amdgcn_global_load_lds((gptr_t)g, (lptr_t)(lp + sub * 512), 16, 0, 0);
}

// ==== SPLIT GEMM (round-10 proven): all-NT, BK=64, single-buffer, 3 MFMA ====
// OM: 0 f32 store*scale | 1 f32 += | 3 f32 += gate[row*gst]*v (non-atomic)
//     4 plane store | 5 vT plane store | 6 scatter += gate via rowmap
template<int MT, int OM>
__global__ __launch_bounds__(256)
void gemms_nt(const u16* __restrict__ Ah, const u16* __restrict__ Al, long ab, int lda,
              const u16* __restrict__ Bh, const u16* __restrict__ Bl, long bb, int ldb,
              void* __restrict__ Cv, long cb, int ldc, long cpl,
              int K, float scale, const float* __restrict__ aux, int gst, int ny,
              const int* __restrict__ rowmap, const int* __restrict__ cntp)
{
  __shared__ __align__(16) u16 ash[MT*32][64], asl[MT*32][64];
  __shared__ __align__(16) u16 bsh[128][64], bsl[128][64];
  const int z = blockIdx.z;
  Ah += (long)z * ab; Al += (long)z * ab;
  Bh += (long)z * bb; Bl += (long)z * bb;
  const int2 tt = tile_xy(ny);
  const int m0 = tt.y * (MT*32), n0 = tt.x * 128;
  int cntv = 1 << 30;
  if (cntp){ cntv = cntp[z]; if (m0 >= cntv) return; }
  const int tid = threadIdx.x, lane = tid & 63, wv = tid >> 6;
  const int wr = (wv >> 1) * (MT*16), wc = (wv & 1) * 64;
  const int fr = lane & 15, fk = (lane >> 4) * 8;

  f32x4 acc[MT][4] = {};
  constexpr int AI4 = MT * 4;

  for (int k0 = 0; k0 < K; k0 += 64){
    __syncthreads();
    #pragma unroll
    for (int ii = 0; ii < 2*AI4 + 32; ++ii){
      if ((ii & 3) != wv) continue;
      if (ii < AI4)             stage64(Ah, lda, m0, k0, &ash[0][0], ii, lane);
      else if (ii < 2*AI4)      stage64(Al, lda, m0, k0, &asl[0][0], ii - AI4, lane);
      else if (ii < 2*AI4 + 16) stage64(Bh, ldb, n0, k0, &bsh[0][0], ii - 2*AI4, lane);
      else                      stage64(Bl, ldb, n0, k0, &bsl[0][0], ii - 2*AI4 - 16, lane);
    }
    __syncthreads();
    bf16x8 ahf[MT][2], alf[MT][2], bhf[4][2], blf[4][2];
    #pragma unroll
    for (int mi = 0; mi < MT; ++mi){
      const int rr = wr + mi * 16 + fr;
      #pragma unroll
      for (int ks = 0; ks < 2; ++ks){
        const int sc = swz64(rr, ks * 32 + fk);
        ahf[mi][ks] = *(const bf16x8*)&ash[rr][sc];
        alf[mi][ks] = *(const bf16x8*)&asl[rr][sc];
      }
    }
    #pragma unroll
    for (int ni = 0; ni < 4; ++ni){
      const int rr = wc + ni * 16 + fr;
      #pragma unroll
      for (int ks = 0; ks < 2; ++ks){
        const int sc = swz64(rr, ks * 32 + fk);
        bhf[ni][ks] = *(const bf16x8*)&bsh[rr][sc];
        blf[ni][ks] = *(const bf16x8*)&bsl[rr][sc];
      }
    }
    #pragma unroll
    for (int mi = 0; mi < MT; ++mi)
      #pragma unroll
      for (int ni = 0; ni < 4; ++ni)
        #pragma unroll
        for (int ks = 0; ks < 2; ++ks){
          acc[mi][ni] = __builtin_amdgcn_mfma_f32_16x16x32_bf16(ahf[mi][ks], bhf[ni][ks], acc[mi][ni], 0, 0, 0);
          acc[mi][ni] = __builtin_amdgcn_mfma_f32_16x16x32_bf16(ahf[mi][ks], blf[ni][ks], acc[mi][ni], 0, 0, 0);
          acc[mi][ni] = __builtin_amdgcn_mfma_f32_16x16x32_bf16(alf[mi][ks], bhf[ni][ks], acc[mi][ni], 0, 0, 0);
        }
  }

  const int crow = (lane >> 4) * 4, ccol = lane & 15;
  #pragma unroll
  for (int mi = 0; mi < MT; ++mi){
    #pragma unroll
    for (int ni = 0; ni < 4; ++ni){
      const int gm0 = m0 + wr + mi * 16 + crow;
      const int gn = n0 + wc + ni * 16 + ccol;
      if (OM == 5){
        u16 hv[4], lv[4];
        #pragma unroll
        for (int j = 0; j < 4; ++j) split1(acc[mi][ni][j], hv[j], lv[j]);
        const long off = (((long)(gm0 >> 10) * 16 + (gn >> 7)) * 128 + (gn & 127)) * 1024 + (gm0 & 1023);
        u16* vt = (u16*)Cv;
        *(int2*)(vt + off) = *(const int2*)hv;
        *(int2*)(vt + cpl + off) = *(const int2*)lv;
      } else if (OM == 6){
        #pragma unroll
        for (int j = 0; j < 4; ++j){
          const int row = gm0 + j;
          if (row < cntv){
            const long t = rowmap[(long)z * CAP + row];
            ((float*)Cv)[t * ldc + gn] += aux[t * gst] * acc[mi][ni][j];
          }
        }
      } else {
        #pragma unroll
        for (int j = 0; j < 4; ++j){
          const long off = (long)z * cb + (long)(gm0 + j) * ldc + gn;
          const float v = acc[mi][ni][j];
          if (OM == 0)      ((float*)Cv)[off] = v * scale;
          else if (OM == 1) ((float*)Cv)[off] += v;
          else if (OM == 3) ((float*)Cv)[off] += aux[(long)(gm0 + j) * gst] * v;
          else { u16 hv, lv; split1(v, hv, lv); ((u16*)Cv)[off] = hv; ((u16*)Cv)[off + cpl] = lv; }
        }
      }
    }
  }
}

// ==== PLAIN BF16 GEMM (round-9 proven): NT, BK=32, single-buffer ====
// OM: 0 bf16 store | 2 f32 store + bias | 3 f32 atomicAdd(gate) | 7 atomic scatter via rowmap
template<int MT, int OM>
__global__ __launch_bounds__(256)
void gemmb_nt(const bf16* __restrict__ A, long ab, int lda,
              const bf16* __restrict__ B, long bb, int ldb,
              void* __restrict__ Cv, long cb, int ldc,
              int K, const float* __restrict__ aux, int gst, int ny,
              const int* __restrict__ rowmap, const int* __restrict__ cntp)
{
  __shared__ __align__(16) u16 a_lds[MT*32][32];
  __shared__ __align__(16) u16 b_lds[128][32];
  const int z = blockIdx.z;
  A += (long)z * ab; B += (long)z * bb;
  const int2 tt = tile_xy(ny);
  const int m0 = tt.y * (MT*32), n0 = tt.x * 128;
  int cntv = 1 << 30;
  if (cntp){ cntv = cntp[z]; if (m0 >= cntv) return; }
  const int tid = threadIdx.x, lane = tid & 63, wv = tid >> 6;
  const int wr = (wv >> 1) * (MT*16), wc = (wv & 1) * 64;
  const int fr = lane & 15, fk = (lane >> 4) * 8;

  f32x4 acc[MT][4] = {};
  constexpr int AI = MT * 2;

  for (int k0 = 0; k0 < K; k0 += 32){
    __syncthreads();
    #pragma unroll
    for (int ii = 0; ii < AI + 8; ++ii){
      if ((ii & 3) != wv) continue;
      if (ii < AI) stage32((const u16*)A, lda, m0, k0, &a_lds[0][0], ii, lane);
      else         stage32((const u16*)B, ldb, n0, k0, &b_lds[0][0], ii - AI, lane);
    }
    __syncthreads();
    bf16x8 af[MT], bfv[4];
    #pragma unroll
    for (int mi = 0; mi < MT; ++mi){
      const int rr = wr + mi * 16 + fr;
      af[mi] = *(const bf16x8*)&a_lds[rr][swz2(rr, fk)];
    }
    #pragma unroll
    for (int ni = 0; ni < 4; ++ni){
      const int rr = wc + ni * 16 + fr;
      bfv[ni] = *(const bf16x8*)&b_lds[rr][swz2(rr, fk)];
    }
    #pragma unroll
    for (int mi = 0; mi < MT; ++mi)
      #pragma unroll
      for (int ni = 0; ni < 4; ++ni)
        acc[mi][ni] = __builtin_amdgcn_mfma_f32_16x16x32_bf16(af[mi], bfv[ni], acc[mi][ni], 0, 0, 0);
  }

  const int crow = (lane >> 4) * 4, ccol = lane & 15;
  #pragma unroll
  for (int mi = 0; mi < MT; ++mi){
    #pragma unroll
    for (int ni = 0; ni < 4; ++ni){
      const int gm0 = m0 + wr + mi * 16 + crow;
      const int gn = n0 + wc + ni * 16 + ccol;
      #pragma unroll
      for (int j = 0; j < 4; ++j){
        const float v = acc[mi][ni][j];
        if (OM == 7){
          const int row = gm0 + j;
          if (row < cntv){
            const long t = rowmap[(long)z * CAP + row];
            atomicAdd(&((float*)Cv)[t * ldc + gn], aux[t * gst + z] * v);
          }
        } else {
          const long off = (long)z * cb + (long)(gm0 + j) * ldc + gn;
          if (OM == 0)      ((bf16*)Cv)[off] = f2b(v);
          else if (OM == 2) ((float*)Cv)[off] = v + aux[gn];
          else              atomicAdd(&((float*)Cv)[off], aux[(long)(gm0 + j) * gst + z] * v);
        }
      }
    }
  }
}

extern "C" void kernel_launch(void* const* d_in, const int* in_sizes, int n_in,
                              void* d_out, int out_size, void* d_ws, size_t ws_size,
                              hipStream_t stream)
{
  (void)in_sizes; (void)n_in; (void)out_size; (void)ws_size;
  const int*   toks = (const int*)d_in[0];
  const float* emb  = (const float*)d_in[1];
  const float* enw  = (const float*)d_in[2];
  const float* nw   = (const float*)d_in[3];
  const float* Wq   = (const float*)d_in[4];
  const float* Wdkv = (const float*)d_in[5];
  const float* Wuk  = (const float*)d_in[6];
  const float* Wuv  = (const float*)d_in[7];
  const float* Wo   = (const float*)d_in[8];
  const float* Wg   = (const float*)d_in[9];
  const float* W1   = (const float*)d_in[10];
  const float* W3   = (const float*)d_in[11];
  const float* W2   = (const float*)d_in[12];
  const float* hnw  = (const float*)d_in[13];
  const float* hW   = (const float*)d_in[14];
  const float* hb   = (const float*)d_in[15];

  const size_t MB = 1ull << 20;
  char* ws = (char*)d_ws;
  float* h    = (float*)(ws);               // [0,16)
  float* gw   = (float*)(ws + 16*MB);       // gates [T][4] (32 KB)
  int*   idx  = (int*)(ws + 16*MB + 128*1024); // [4][CAP]
  int*   cnt  = (int*)(ws + 16*MB + 256*1024); // [4]
  u16*   xph  = (u16*)(ws + 17*MB);         // [17,33)  x planes (lo = +PL_X)
  u16*   wpl  = (u16*)(ws + 33*MB);         // [33,49)  weight planes scratch
  u16*   qph  = (u16*)(ws + 49*MB);         // [49,65)
  u16*   cph  = (u16*)(ws + 65*MB);         // [65,69)
  u16*   kph  = (u16*)(ws + 69*MB);         // [69,85)
  u16*   vtp  = (u16*)(ws + 85*MB);         // [85,101) v transposed planes
  u16*   oph  = (u16*)(ws + 101*MB);        // [101,117)
  float* pf   = (float*)(ws + 17*MB);       // [17,49)  scores (attn core)
  u16*   xg   = (u16*)(ws + 49*MB);         // l0 MoE: gathered pair planes = 24MB
  float* h1f  = (float*)(ws + 73*MB);       // [73,85)
  float* h3f  = (float*)(ws + 85*MB);       // [85,97)
  bf16*  wT   = (bf16*)(ws + 33*MB);        // l1 bf16 weights [33,49)
  u16*   xgb  = (u16*)(ws + 49*MB);         // l1: gathered bf16 = 24MB
  bf16*  h1b  = (bf16*)(ws + 73*MB);        // [73,85)
  bf16*  h3b  = (bf16*)(ws + 85*MB);        // [85,97)
  bf16*  whT  = (bf16*)(ws + 33*MB);        // head wT half: 62.5MB [33,95.5)

  const float qscale = 0.08838834764831845f;

  embed_norm_k<<<TOKS, 256, 0, stream>>>(toks, emb, enw, h);

  for (int l = 0; l < 2; ++l){
    const float* nwl = nw + (long)l * DM;
    rmsnorm_planes_k<<<TOKS, 256, 0, stream>>>(h, nwl, xph, xph + PL_X);

    // q = x @ Wq
    tsplit_k<<<1024, 256, 0, stream>>>(Wq + (long)l*DM*DM, 0, DM, wpl, wpl + M4, 0, DM, 32);
    gemms_nt<2,4><<<dim3(512,1,1), 256, 0, stream>>>(xph, xph + PL_X, 0, DM, wpl, wpl + M4, 0, DM,
        qph, 0, DM, PL_X, DM, 1.f, nullptr, 0, 32, nullptr, nullptr);
    // c = x @ Wdkv
    tsplit_k<<<256, 256, 0, stream>>>(Wdkv + (long)l*DM*RL, 0, RL, wpl, wpl + M2, 0, DM, 8);
    gemms_nt<2,4><<<dim3(128,1,1), 256, 0, stream>>>(xph, xph + PL_X, 0, DM, wpl, wpl + M2, 0, DM,
        cph, 0, RL, PL_C, DM, 1.f, nullptr, 0, 32, nullptr, nullptr);
    // k = c @ Wuk
    tsplit_k<<<256, 256, 0, stream>>>(Wuk + (long)l*RL*DM, 0, DM, wpl, wpl + M2, 0, RL, 32);
    gemms_nt<2,4><<<dim3(512,1,1), 256, 0, stream>>>(cph, cph + PL_C, 0, RL, wpl, wpl + M2, 0, RL,
        kph, 0, DM, PL_X, RL, 1.f, nullptr, 0, 32, nullptr, nullptr);
    // v = c @ Wuv -> vT planes
    tsplit_k<<<256, 256, 0, stream>>>(Wuv + (long)l*RL*DM, 0, DM, wpl, wpl + M2, 0, RL, 32);
    gemms_nt<2,5><<<dim3(512,1,1), 256, 0, stream>>>(cph, cph + PL_C, 0, RL, wpl, wpl + M2, 0, RL,
        vtp, 0, 0, PL_VT, RL, 1.f, nullptr, 0, 32, nullptr, nullptr);

    // attention core: per batch x 8-head group
    for (int b = 0; b < 2; ++b){
      for (int hg = 0; hg < 2; ++hg){
        const long qo = (long)b*SQ*DM + hg*1024;
        gemms_nt<4,0><<<dim3(64,1,8), 256, 0, stream>>>(qph + qo, qph + PL_X + qo, 128, DM,
            kph + qo, kph + PL_X + qo, 128, DM,
            pf, (long)SQ*SQ, SQ, 0, 128, qscale, nullptr, 0, 8, nullptr, nullptr);
        softmax_pack_k<<<8*SQ, 256, 0, stream>>>(pf);
        const long vo = ((long)b*16 + hg*8) * 128 * 1024;
        gemms_nt<1,4><<<dim3(32,1,8), 256, 0, stream>>>((const u16*)pf, (const u16*)pf + 1024,
            1024l*2048, 2048,
            vtp + vo, vtp + PL_VT + vo, 128l*1024, 1024,
            oph + (long)b*SQ*DM + hg*1024, 128, DM, PL_X, SQ, 1.f, nullptr, 0, 32, nullptr, nullptr);
      }
    }

    // h += o @ Wo
    tsplit_k<<<1024, 256, 0, stream>>>(Wo + (long)l*DM*DM, 0, DM, wpl, wpl + M4, 0, DM, 32);
    gemms_nt<2,1><<<dim3(512,1,1), 256, 0, stream>>>(oph, oph + PL_X, 0, DM, wpl, wpl + M4, 0, DM,
        h, 0, DM, 0, DM, 1.f, nullptr, 0, 32, nullptr, nullptr);

    gate_k<<<TOKS, 256, 0, stream>>>(h, nwl, Wg + (long)l*DM*4, gw);
    build_lists_k<<<1, 256, 0, stream>>>(gw, idx, cnt);
    rmsnorm_planes_k<<<TOKS, 256, 0, stream>>>(h, nwl, xph, xph + PL_X);

    if (l == 0){
      // precise sparse MoE, expert pairs; deterministic scatter-accumulate
      for (int p2 = 0; p2 < 2; ++p2){
        const int ebase = p2 * 2;
        const long wo13 = ((long)l*4 + ebase) * (long)DM * DF;
        gather2_k<<<2*CAP, 256, 0, stream>>>(xph, idx, cnt, ebase, xg);
        tsplit_k<<<dim3(512,1,2), 256, 0, stream>>>(W1 + wo13, (long)DM*DF, DF, wpl, wpl + M4, M2, DM, 16);
        gemms_nt<2,0><<<dim3(192,1,2), 256, 0, stream>>>(xg, xg + (long)CAP*DM, 2l*CAP*DM, DM,
            wpl, wpl + M4, M2, DM, h1f, (long)CAP*DF, DF, 0, DM, 1.f, nullptr, 0, 24,
            nullptr, cnt + ebase);
        tsplit_k<<<dim3(512,1,2), 256, 0, stream>>>(W3 + wo13, (long)DM*DF, DF, wpl, wpl + M4, M2, DM, 16);
        gemms_nt<2,0><<<dim3(192,1,2), 256, 0, stream>>>(xg, xg + (long)CAP*DM, 2l*CAP*DM, DM,
            wpl, wpl + M4, M2, DM, h3f, (long)CAP*DF, DF, 0, DM, 1.f, nullptr, 0, 24,
            nullptr, cnt + ebase);
        swiglu_pack_k<<<CAP, 256, 0, stream>>>(h1f, h3f);
        tsplit_k<<<dim3(512,1,2), 256, 0, stream>>>(W2 + ((long)l*4 + ebase)*(long)DF*DM, (long)DF*DM, DM,
            wpl, wpl + M4, M2, DF, 32);
        for (int ei = 0; ei < 2; ++ei){
          gemms_nt<2,6><<<dim3(384,1,1), 256, 0, stream>>>(
              (const u16*)h1f + (long)ei*CAP*2048, (const u16*)h1f + (long)ei*CAP*2048 + 1024,
              0, 2048, wpl + (long)ei*M2, wpl + M4 + (long)ei*M2, 0, DF,
              h, 0, DM, 0, DF, 1.f, gw + ebase + ei, 4, 24,
              idx + (ebase + ei)*CAP, cnt + ebase + ei);
        }
      }
    } else {
      // fast sparse bf16 MoE, all 4 experts (z=4); atomic scatter (head-only consumer)
      gatherb_k<<<4*CAP, 256, 0, stream>>>(xph, idx, cnt, xgb);
      tconv_k<<<dim3(512,1,4), 256, 0, stream>>>(W1 + (long)l*4*DM*DF, (long)DM*DF, DF, wT, M2, DM, 16);
      gemmb_nt<2,0><<<dim3(192,1,4), 256, 0, stream>>>((const bf16*)xgb, (long)CAP*DM, DM, wT, M2, DM,
          h1b, (long)CAP*DF, DF, DM, nullptr, 0, 24, nullptr, cnt);
      tconv_k<<<dim3(512,1,4), 256, 0, stream>>>(W3 + (long)l*4*DM*DF, (long)DM*DF, DF, wT, M2, DM, 16);
      gemmb_nt<2,0><<<dim3(192,1,4), 256, 0, stream>>>((const bf16*)xgb, (long)CAP*DM, DM, wT, M2, DM,
          h3b, (long)CAP*DF, DF, DM, nullptr, 0, 24, nullptr, cnt);
      swiglu_bk<<<(4*CAP*DF)/2048, 256, 0, stream>>>(h1b, h3b);
      tconv_k<<<dim3(512,1,4), 256, 0, stream>>>(W2 + (long)l*4*DF*DM, (long)DF*DM, DM, wT, M2, DF, 32);
      gemmb_nt<2,7><<<dim3(384,1,4), 256, 0, stream>>>(h1b, (long)CAP*DF, DF, wT, M2, DF,
          h, 0, DM, DF, gw, 4, 24, idx, cnt);
    }
  }

  // head: two N-halves, transposed bf16 weights
  rmsnorm_planes_k<<<TOKS, 256, 0, stream>>>(h, hnw, xph, xph + PL_X);
  for (int half = 0; half < 2; ++half){
    tconv_k<<<8000, 256, 0, stream>>>(hW + half*16000, 0, NV, whT, 0, DM, 250);
    gemmb_nt<4,2><<<dim3(2000,1,1), 256, 0, stream>>>((const bf16*)xph, 0, DM, whT, 0, DM,
        (float*)d_out + half*16000, 0, NV, DM, hb + half*16000, 0, 16, nullptr, nullptr);
  }
}